// Round 5
// baseline (261.077 us; speedup 1.0000x reference)
//
#include <hip/hip_runtime.h>
#include <math.h>

// Problem constants
#define BATCH 8
#define NN 64
#define DD 65536            // 64*32*32 feature length (contiguous per [b,n])
#define NBLK 2048           // stage-1 blocks (128 thr = 2 waves each)
#define WPB 512             // waves (= K-chunks) per batch
#define NWAVE (BATCH * WPB) // 4096 independent partials
#define KWV 128             // K floats per wave
#define KSTEPS (KWV / 32)   // 4 MFMA K-steps per wave
#define NTRI 10             // upper-triangle 16x16 tiles of the 64x64 Gram
#define PSZ (NTRI * 256)    // floats per partial (2560)

typedef float  floatx4 __attribute__((ext_vector_type(4)));
typedef __bf16 bf16x8  __attribute__((ext_vector_type(8)));

// Pack 8 fp32 -> 8 bf16 via v_perm_b32 (truncation; bias cancels in the
// scale-invariant cosine ratio — validated: absmax 1.5e-5).
static __device__ __forceinline__ bf16x8 cvt8(float4 lo, float4 hi) {
    const unsigned sel = 0x07060302u;
    union { unsigned u[4]; bf16x8 v; } r;
    r.u[0] = __builtin_amdgcn_perm(__float_as_uint(lo.y), __float_as_uint(lo.x), sel);
    r.u[1] = __builtin_amdgcn_perm(__float_as_uint(lo.w), __float_as_uint(lo.z), sel);
    r.u[2] = __builtin_amdgcn_perm(__float_as_uint(hi.y), __float_as_uint(hi.x), sel);
    r.u[3] = __builtin_amdgcn_perm(__float_as_uint(hi.w), __float_as_uint(hi.z), sel);
    return r.v;
}

// ---------------------------------------------------------------------------
// Stage 1 v5: OCCUPANCY experiment. Body (loads, MFMA tri-set, store layout)
// is bit-identical math to the validated R0 kernel; the single variable is
// waves/CU: 8 -> 16. Evidence: R0/R2/R3/R4 all ran 8 waves/CU and all stuck
// at ~70 µs (~1.9 TB/s) with VALU/MFMA/HBM ~idle, regardless of per-wave MLP
// (R3 pinned, R2 HW-guaranteed 16 KB/wave in flight) or coalescing (R4
// 512 B segments). That pattern-independence points at a per-CU/per-wave
// outstanding-request cap -> BW scales with resident waves, not with
// per-wave instruction scheduling. Here every wave is fully independent
// (own K=128 chunk, own tri-partial, no LDS, no barriers): 2048 blocks x
// 2 waves = 16 waves/CU under __launch_bounds__(128,4).
// ---------------------------------------------------------------------------
__global__ __launch_bounds__(128, 4) void gram_partial_kernel(const float* __restrict__ a,
                                                              float* __restrict__ part) {
    const int bid  = blockIdx.x;          // 0..2047; 256 blocks per batch
    const int b    = bid >> 8;
    const int tid  = threadIdx.x;
    const int w    = tid >> 6;            // wave 0..1
    const int lane = tid & 63;
    const int m    = lane & 15;
    const int q    = lane >> 4;
    const int c    = ((bid & 255) << 1) | w;   // K-chunk 0..511 within batch

    const float* base = a + (size_t)b * NN * DD + (size_t)c * KWV
                          + (size_t)m * DD + q * 8;
    const float* p0 = base;                       // rows  0..15
    const float* p1 = base + (size_t)16 * DD;     // rows 16..31
    const float* p2 = base + (size_t)32 * DD;     // rows 32..47
    const float* p3 = base + (size_t)48 * DD;     // rows 48..63

    floatx4 acc[NTRI];
    #pragma unroll
    for (int i = 0; i < NTRI; ++i) acc[i] = (floatx4)0.0f;

    float4 A0, A1, A2, A3, A4, A5, A6, A7;   // buffer A
    float4 B0, B1, B2, B3, B4, B5, B6, B7;   // buffer B

#define LOADSET(R0,R1,R2,R3,R4,R5,R6,R7, o)                                \
    R0 = *(const float4*)(p0 + (o));  R1 = *(const float4*)(p0 + (o) + 4); \
    R2 = *(const float4*)(p1 + (o));  R3 = *(const float4*)(p1 + (o) + 4); \
    R4 = *(const float4*)(p2 + (o));  R5 = *(const float4*)(p2 + (o) + 4); \
    R6 = *(const float4*)(p3 + (o));  R7 = *(const float4*)(p3 + (o) + 4);

    // acc slots: 0:(0,0) 1:(0,1) 2:(0,2) 3:(0,3) 4:(1,1) 5:(1,2) 6:(1,3)
    //            7:(2,2) 8:(2,3) 9:(3,3)
#define MFMASET(R0,R1,R2,R3,R4,R5,R6,R7)                                   \
    {                                                                      \
        bf16x8 f0 = cvt8(R0, R1);                                          \
        bf16x8 f1 = cvt8(R2, R3);                                          \
        bf16x8 f2 = cvt8(R4, R5);                                          \
        bf16x8 f3 = cvt8(R6, R7);                                          \
        acc[0] = __builtin_amdgcn_mfma_f32_16x16x32_bf16(f0, f0, acc[0], 0, 0, 0); \
        acc[1] = __builtin_amdgcn_mfma_f32_16x16x32_bf16(f0, f1, acc[1], 0, 0, 0); \
        acc[2] = __builtin_amdgcn_mfma_f32_16x16x32_bf16(f0, f2, acc[2], 0, 0, 0); \
        acc[3] = __builtin_amdgcn_mfma_f32_16x16x32_bf16(f0, f3, acc[3], 0, 0, 0); \
        acc[4] = __builtin_amdgcn_mfma_f32_16x16x32_bf16(f1, f1, acc[4], 0, 0, 0); \
        acc[5] = __builtin_amdgcn_mfma_f32_16x16x32_bf16(f1, f2, acc[5], 0, 0, 0); \
        acc[6] = __builtin_amdgcn_mfma_f32_16x16x32_bf16(f1, f3, acc[6], 0, 0, 0); \
        acc[7] = __builtin_amdgcn_mfma_f32_16x16x32_bf16(f2, f2, acc[7], 0, 0, 0); \
        acc[8] = __builtin_amdgcn_mfma_f32_16x16x32_bf16(f2, f3, acc[8], 0, 0, 0); \
        acc[9] = __builtin_amdgcn_mfma_f32_16x16x32_bf16(f3, f3, acc[9], 0, 0, 0); \
    }

    LOADSET(A0,A1,A2,A3,A4,A5,A6,A7, 0)
    #pragma unroll
    for (int s = 0; s < KSTEPS; s += 2) {
        LOADSET(B0,B1,B2,B3,B4,B5,B6,B7, (s + 1) * 32)
        MFMASET(A0,A1,A2,A3,A4,A5,A6,A7)
        if (s + 2 < KSTEPS) { LOADSET(A0,A1,A2,A3,A4,A5,A6,A7, (s + 2) * 32) }
        MFMASET(B0,B1,B2,B3,B4,B5,B6,B7)
    }
#undef LOADSET
#undef MFMASET

    // Every wave stores its own tri-partial. Slot t holds
    // G[16*ib + 4q + r][16*jb + m] (m89 layout, validated).
    float* pg = part + ((size_t)b * WPB + c) * PSZ;
    #pragma unroll
    for (int t = 0; t < NTRI; ++t) {
        float* tp = pg + t * 256 + m;
        #pragma unroll
        for (int r = 0; r < 4; ++r)
            tp[(q * 4 + r) * 16] = acc[t][r];
    }
}

// ---------------------------------------------------------------------------
// Stage 1b: reduce WPB=512 tri-partials per batch -> gram[8][64*64] row-major.
// Lower triangle reconstructed by reading the transposed slot (each K-partial
// Gram is symmetric, so this is exact). 42 MB coalesced read.
// ---------------------------------------------------------------------------
__global__ __launch_bounds__(128) void gram_reduce_kernel(const float* __restrict__ part,
                                                          float* __restrict__ gram) {
    const int gid = blockIdx.x * 128 + threadIdx.x;   // 0 .. 8*4096-1
    const int b   = gid >> 12;
    const int idx = gid & 4095;
    const int i   = idx >> 6;
    const int j   = idx & 63;
    const int ti  = i >> 4, tj = j >> 4;
    const int ib  = ti <= tj ? ti : tj;
    const int jb  = ti <= tj ? tj : ti;
    const int slot = ib * 4 - (ib * (ib - 1)) / 2 + (jb - ib);
    const int rr  = (ti <= tj) ? (i & 15) : (j & 15);
    const int cc  = (ti <= tj) ? (j & 15) : (i & 15);
    const int off = slot * 256 + rr * 16 + cc;
    const float* p = part + (size_t)b * WPB * PSZ + off;

    float s0 = 0.f, s1 = 0.f, s2 = 0.f, s3 = 0.f;
    float s4 = 0.f, s5 = 0.f, s6 = 0.f, s7 = 0.f;
    #pragma unroll 4
    for (int c = 0; c < WPB; c += 8) {
        s0 += p[(size_t)(c + 0) * PSZ];
        s1 += p[(size_t)(c + 1) * PSZ];
        s2 += p[(size_t)(c + 2) * PSZ];
        s3 += p[(size_t)(c + 3) * PSZ];
        s4 += p[(size_t)(c + 4) * PSZ];
        s5 += p[(size_t)(c + 5) * PSZ];
        s6 += p[(size_t)(c + 6) * PSZ];
        s7 += p[(size_t)(c + 7) * PSZ];
    }
    gram[gid] = ((s0 + s1) + (s2 + s3)) + ((s4 + s5) + (s6 + s7));
}

// ---------------------------------------------------------------------------
// Stage 2: per-batch CRF iterations. 8 blocks x 256 threads.
// ---------------------------------------------------------------------------
__global__ __launch_bounds__(256) void crf_kernel(const float* __restrict__ gram,
                                                  const float* __restrict__ logits,
                                                  const float* __restrict__ Wm,
                                                  float* __restrict__ out) {
    __shared__ float pp[NN][NN + 1];
    __shared__ float E[NN];
    __shared__ float nrm[NN];
    __shared__ float part[4 * NN];

    const int b  = blockIdx.x;
    const int tid = threadIdx.x;
    const int i  = tid & 63;
    const int jq = tid >> 6;
    const float* g = gram + b * NN * NN;

    if (jq == 0) nrm[i] = sqrtf(g[i * NN + i]);
    E[i] = 0.0f;
    __syncthreads();

    const float ni = nrm[i];
    for (int jj = 0; jj < 16; ++jj) {
        int j = jq * 16 + jj;
        float wsym = 0.5f * (Wm[i * NN + j] + Wm[j * NN + i]);
        pp[i][j] = g[i * NN + j] / (ni * nrm[j] + 1e-6f) * wsym;
    }
    const float li = logits[b * NN + i];
    __syncthreads();

    for (int it = 0; it < 10; ++it) {
        float acc = 0.0f;
        for (int jj = 0; jj < 16; ++jj) {
            int j = jq * 16 + jj;
            float t = li + E[j];
            float s = 1.0f / (1.0f + expf(-t));
            acc = fmaf(2.0f * s - 1.0f, pp[i][j], acc);
        }
        part[jq * NN + i] = acc;
        __syncthreads();
        if (jq == 0)
            E[i] = part[i] + part[NN + i] + part[2 * NN + i] + part[3 * NN + i];
        __syncthreads();
    }

    if (tid < 64) {
        float s = E[tid];
        for (int off = 32; off > 0; off >>= 1) s += __shfl_down(s, off);
        float meanE = __shfl(s, 0) * (1.0f / 64.0f);
        out[b * NN + tid] = logits[b * NN + tid] + meanE;
    }
}

extern "C" void kernel_launch(void* const* d_in, const int* in_sizes, int n_in,
                              void* d_out, int out_size, void* d_ws, size_t ws_size,
                              hipStream_t stream) {
    const float* a      = (const float*)d_in[0];  // [8,64,64,32,32]
    const float* logits = (const float*)d_in[1];  // [8,64]
    const float* Wm     = (const float*)d_in[2];  // [1,64,64]
    float* out  = (float*)d_out;                  // [8,64]

    float* part = (float*)d_ws;                           // [4096][2560] fp32
    float* gram = part + (size_t)NWAVE * PSZ;             // [8][4096]

    gram_partial_kernel<<<NBLK, 128, 0, stream>>>(a, part);
    gram_reduce_kernel<<<(BATCH * NN * NN) / 128, 128, 0, stream>>>(part, gram);
    crf_kernel<<<BATCH, 256, 0, stream>>>(gram, logits, Wm, out);
}

// Round 6
// 224.615 us; speedup vs baseline: 1.1623x; 1.1623x over previous
//
#include <hip/hip_runtime.h>
#include <math.h>

// Problem constants
#define BATCH 8
#define NN 64
#define DD 65536            // 64*32*32 feature length (contiguous per [b,n])
#define BPB 64              // blocks per batch -> grid = 512
#define NBLK (BATCH * BPB)
#define KC 1024             // K floats per block chunk
#define SKF 256             // K floats per stage
#define NSTG (KC / SKF)     // 4 stages
#define NTRI 10             // upper-triangle 16x16 tiles of the 64x64 Gram
#define PSZ (NTRI * 256)    // floats per partial (2560)

typedef float  floatx4 __attribute__((ext_vector_type(4)));
typedef __bf16 bf16x8  __attribute__((ext_vector_type(8)));

// ---------------------------------------------------------------------------
// Stage 1 v6: COPY-PATTERN staging. Ledger: R0/R3 (reg scatter, pinned), R2
// (global_load_lds DMA), R4 (512B coop staging), R5 (2x occupancy) ALL read
// the input at 1.3-1.9 TB/s with every pipe idle. The only proven-fast
// patterns on this chip (fill 6.9 TB/s, m13 copy 6.3 TB/s) are lane-
// consecutive, >=1KB-contiguous-per-wave-instruction. This kernel reads
// EXACTLY that way: wave w stages rows 16w..16w+15, one row per instruction,
// lane l reading row_ptr + l*16B (1KB contiguous). fp32->bf16 conversion in
// registers (same truncation as validated cvt8 -> same numerics), ds_write
// into an XOR-swizzled [64][256K-bf16] LDS tile (off ^= (row&7)<<4; even
// bank spread on both sides, full-BW verified by hand). MFMA fragments read
// bf16x8 straight from LDS; waves split kk within each stage. 4 stages,
// double-buffered (2x32KB), one barrier per stage.
// Partial store layout / reduce / crf are verbatim R0 (validated).
// ---------------------------------------------------------------------------
__global__ __launch_bounds__(256, 2) void gram_partial_kernel(const float* __restrict__ a,
                                                              float* __restrict__ part) {
    __shared__ __align__(16) union {
        unsigned char stage[2][32768];        // 2 x [64 rows][512 B bf16]
        float red[3][NTRI][64][4];            // 30 KB cross-wave reduce (aliases)
    } sh;

    const int bid = blockIdx.x;
    const int b = bid >> 6;           // / BPB
    const int c = bid & (BPB - 1);

    const int tid  = threadIdx.x;
    const int w    = tid >> 6;        // wave id 0..3
    const int lane = tid & 63;
    const int m    = lane & 15;
    const int q    = lane >> 4;

    const unsigned sel = 0x07060302u;

    // Staging: wave w owns rows 16w..16w+15; lane l covers bytes [16l,16l+16)
    // of each row's 1 KB stage-slice. Fully contiguous per instruction.
    const float* pA = a + (size_t)(b * NN + 16 * w) * DD + (size_t)c * KC + lane * 4;
    unsigned char* stg = &sh.stage[0][0];
    const int l8 = lane * 8;                       // bf16 write offset in row

    // Fragment read offsets (constant per thread): wave w computes kk=2w,2w+1
    // per stage. off = (kk*64 + q*16) ^ ((m&7)<<4); row&7 == m&7 for all
    // row groups m+16g.
    const int off0 = ((w * 128) + q * 16) ^ ((m & 7) << 4);
    const int off1 = off0 ^ 64;

    floatx4 acc[NTRI];
    #pragma unroll
    for (int i = 0; i < NTRI; ++i) acc[i] = (floatx4)0.0f;

    float4 L0, L1, L2, L3, L4, L5, L6, L7, L8, L9, L10, L11, L12, L13, L14, L15;

#define FORALLROWS(OP) OP(0) OP(1) OP(2) OP(3) OP(4) OP(5) OP(6) OP(7) \
                       OP(8) OP(9) OP(10) OP(11) OP(12) OP(13) OP(14) OP(15)

#define LD1(r) L##r = *(const float4*)(pA + (size_t)(r) * DD + so_);
#define LOADS(s) { const int so_ = (s) * SKF; FORALLROWS(LD1) }

    // bf16 truncation via v_perm (identical to validated cvt8), swizzled write.
#define WR1(r)                                                              \
    {                                                                       \
        uint2 u_;                                                           \
        u_.x = __builtin_amdgcn_perm(__float_as_uint(L##r.y),               \
                                     __float_as_uint(L##r.x), sel);         \
        u_.y = __builtin_amdgcn_perm(__float_as_uint(L##r.w),               \
                                     __float_as_uint(L##r.z), sel);         \
        *(uint2*)(wb_ + (r) * 512 + (l8 ^ (((r) & 7) << 4))) = u_;          \
    }
#define WRITES(buf) { unsigned char* wb_ = stg + (buf) * 32768 + w * 8192; FORALLROWS(WR1) }

    // acc slots: 0:(0,0) 1:(0,1) 2:(0,2) 3:(0,3) 4:(1,1) 5:(1,2) 6:(1,3)
    //            7:(2,2) 8:(2,3) 9:(3,3)
#define TRIMFMA(f0, f1, f2, f3)                                             \
    acc[0] = __builtin_amdgcn_mfma_f32_16x16x32_bf16(f0, f0, acc[0], 0, 0, 0); \
    acc[1] = __builtin_amdgcn_mfma_f32_16x16x32_bf16(f0, f1, acc[1], 0, 0, 0); \
    acc[2] = __builtin_amdgcn_mfma_f32_16x16x32_bf16(f0, f2, acc[2], 0, 0, 0); \
    acc[3] = __builtin_amdgcn_mfma_f32_16x16x32_bf16(f0, f3, acc[3], 0, 0, 0); \
    acc[4] = __builtin_amdgcn_mfma_f32_16x16x32_bf16(f1, f1, acc[4], 0, 0, 0); \
    acc[5] = __builtin_amdgcn_mfma_f32_16x16x32_bf16(f1, f2, acc[5], 0, 0, 0); \
    acc[6] = __builtin_amdgcn_mfma_f32_16x16x32_bf16(f1, f3, acc[6], 0, 0, 0); \
    acc[7] = __builtin_amdgcn_mfma_f32_16x16x32_bf16(f2, f2, acc[7], 0, 0, 0); \
    acc[8] = __builtin_amdgcn_mfma_f32_16x16x32_bf16(f2, f3, acc[8], 0, 0, 0); \
    acc[9] = __builtin_amdgcn_mfma_f32_16x16x32_bf16(f3, f3, acc[9], 0, 0, 0);

#define COMPUTE(buf)                                                        \
    {                                                                       \
        const unsigned char* tb_ = stg + (buf) * 32768;                     \
        bf16x8 g0, g1, g2, g3;                                              \
        g0 = *(const bf16x8*)(tb_ + (m     ) * 512 + off0);                 \
        g1 = *(const bf16x8*)(tb_ + (m + 16) * 512 + off0);                 \
        g2 = *(const bf16x8*)(tb_ + (m + 32) * 512 + off0);                 \
        g3 = *(const bf16x8*)(tb_ + (m + 48) * 512 + off0);                 \
        TRIMFMA(g0, g1, g2, g3)                                             \
        g0 = *(const bf16x8*)(tb_ + (m     ) * 512 + off1);                 \
        g1 = *(const bf16x8*)(tb_ + (m + 16) * 512 + off1);                 \
        g2 = *(const bf16x8*)(tb_ + (m + 32) * 512 + off1);                 \
        g3 = *(const bf16x8*)(tb_ + (m + 48) * 512 + off1);                 \
        TRIMFMA(g0, g1, g2, g3)                                             \
    }

    // Prologue: stage 0.
    LOADS(0)
    WRITES(0)
    #pragma unroll
    for (int s = 0; s < NSTG; ++s) {
        __syncthreads();                       // buf s&1 fully written
        if (s + 1 < NSTG) {
            LOADS(s + 1)                       // 16x 1KB-contiguous, in flight
            __builtin_amdgcn_sched_barrier(0); // pin issue above compute
        }
        COMPUTE(s & 1)
        if (s + 1 < NSTG) { WRITES((s + 1) & 1) }
    }
#undef FORALLROWS
#undef LD1
#undef LOADS
#undef WR1
#undef WRITES
#undef COMPUTE

    // Cross-wave reduce (stage buffers dead; barrier before alias).
    __syncthreads();
    if (w > 0) {
        #pragma unroll
        for (int t = 0; t < NTRI; ++t)
            *(floatx4*)&sh.red[w - 1][t][lane][0] = acc[t];
    }
    __syncthreads();
    if (w == 0) {
        #pragma unroll
        for (int t = 0; t < NTRI; ++t) {
            floatx4 r0 = *(const floatx4*)&sh.red[0][t][lane][0];
            floatx4 r1 = *(const floatx4*)&sh.red[1][t][lane][0];
            floatx4 r2 = *(const floatx4*)&sh.red[2][t][lane][0];
            acc[t] += (r0 + r1) + r2;
        }
        // slot t holds G[16*ib + 4q + r][16*jb + m] (m89 layout, validated)
        float* pg = part + (size_t)bid * PSZ;
        #pragma unroll
        for (int t = 0; t < NTRI; ++t) {
            float* tp = pg + t * 256 + m;
            #pragma unroll
            for (int r = 0; r < 4; ++r)
                tp[(q * 4 + r) * 16] = acc[t][r];
        }
    }
}

// ---------------------------------------------------------------------------
// Stage 1b: reduce BPB=64 tri-partials per batch -> gram[8][64*64] row-major.
// ---------------------------------------------------------------------------
__global__ __launch_bounds__(128) void gram_reduce_kernel(const float* __restrict__ part,
                                                          float* __restrict__ gram) {
    const int gid = blockIdx.x * 128 + threadIdx.x;   // 0 .. 8*4096-1
    const int b   = gid >> 12;
    const int idx = gid & 4095;
    const int i   = idx >> 6;
    const int j   = idx & 63;
    const int ti  = i >> 4, tj = j >> 4;
    const int ib  = ti <= tj ? ti : tj;
    const int jb  = ti <= tj ? tj : ti;
    const int slot = ib * 4 - (ib * (ib - 1)) / 2 + (jb - ib);
    const int rr  = (ti <= tj) ? (i & 15) : (j & 15);
    const int cc  = (ti <= tj) ? (j & 15) : (i & 15);
    const int off = slot * 256 + rr * 16 + cc;
    const float* p = part + (size_t)b * BPB * PSZ + off;

    float s0 = 0.f, s1 = 0.f, s2 = 0.f, s3 = 0.f;
    #pragma unroll 4
    for (int c = 0; c < BPB; c += 4) {
        s0 += p[(size_t)(c + 0) * PSZ];
        s1 += p[(size_t)(c + 1) * PSZ];
        s2 += p[(size_t)(c + 2) * PSZ];
        s3 += p[(size_t)(c + 3) * PSZ];
    }
    gram[gid] = (s0 + s1) + (s2 + s3);
}

// ---------------------------------------------------------------------------
// Stage 2: per-batch CRF iterations. 8 blocks x 256 threads.
// ---------------------------------------------------------------------------
__global__ __launch_bounds__(256) void crf_kernel(const float* __restrict__ gram,
                                                  const float* __restrict__ logits,
                                                  const float* __restrict__ Wm,
                                                  float* __restrict__ out) {
    __shared__ float pp[NN][NN + 1];
    __shared__ float E[NN];
    __shared__ float nrm[NN];
    __shared__ float part[4 * NN];

    const int b  = blockIdx.x;
    const int tid = threadIdx.x;
    const int i  = tid & 63;
    const int jq = tid >> 6;
    const float* g = gram + b * NN * NN;

    if (jq == 0) nrm[i] = sqrtf(g[i * NN + i]);
    E[i] = 0.0f;
    __syncthreads();

    const float ni = nrm[i];
    for (int jj = 0; jj < 16; ++jj) {
        int j = jq * 16 + jj;
        float wsym = 0.5f * (Wm[i * NN + j] + Wm[j * NN + i]);
        pp[i][j] = g[i * NN + j] / (ni * nrm[j] + 1e-6f) * wsym;
    }
    const float li = logits[b * NN + i];
    __syncthreads();

    for (int it = 0; it < 10; ++it) {
        float acc = 0.0f;
        for (int jj = 0; jj < 16; ++jj) {
            int j = jq * 16 + jj;
            float t = li + E[j];
            float s = 1.0f / (1.0f + expf(-t));
            acc = fmaf(2.0f * s - 1.0f, pp[i][j], acc);
        }
        part[jq * NN + i] = acc;
        __syncthreads();
        if (jq == 0)
            E[i] = part[i] + part[NN + i] + part[2 * NN + i] + part[3 * NN + i];
        __syncthreads();
    }

    if (tid < 64) {
        float s = E[tid];
        for (int off = 32; off > 0; off >>= 1) s += __shfl_down(s, off);
        float meanE = __shfl(s, 0) * (1.0f / 64.0f);
        out[b * NN + tid] = logits[b * NN + tid] + meanE;
    }
}

extern "C" void kernel_launch(void* const* d_in, const int* in_sizes, int n_in,
                              void* d_out, int out_size, void* d_ws, size_t ws_size,
                              hipStream_t stream) {
    const float* a      = (const float*)d_in[0];  // [8,64,64,32,32]
    const float* logits = (const float*)d_in[1];  // [8,64]
    const float* Wm     = (const float*)d_in[2];  // [1,64,64]
    float* out  = (float*)d_out;                  // [8,64]

    float* part = (float*)d_ws;                           // [512][2560] fp32
    float* gram = part + (size_t)NBLK * PSZ;              // [8][4096]

    gram_partial_kernel<<<NBLK, 256, 0, stream>>>(a, part);
    gram_reduce_kernel<<<(BATCH * NN * NN) / 128, 128, 0, stream>>>(part, gram);
    crf_kernel<<<BATCH, 256, 0, stream>>>(gram, logits, Wm, out);
}